// Round 19
// baseline (33.327 us; speedup 1.0000x reference)
//
#include <hip/hip_runtime.h>

// PullbackMetric, 4 threads/pixel (thread s owns rows {2s,2s+1}), 128-thr blocks.
// G[m][n] = dmu_m^T Si dmu_n + 0.5 tr( (Si dSig_m)(Si dSig_n) )
// Si = Si^T. X = dSx*Si, Y = dSy*Si rows; ONE fused stream of Si rows from LDS
// (quad-broadcast) computes X and Y together (16 b128 reads instead of 2x16).
// dmu assembled via DPP quad all-gather (no LDS round-trip). Si own-rows kept
// in regs from the staging load for the mean term (die before the stream).
// Cov traces via 2-stage Eklundh DPP transpose. DS ops: 45 -> 20 per thread.
// R19 = R18 with the R17 epilogue restored: mp AND c are both quad-partial, so
// combine g = 0.25*mp + 0.125*c per-thread FIRST, then quad-reduce g (R18
// reduced only c -> dropped 3/4 of the mean term, absmax 13.5).

constexpr int SSTRIDE = 68;   // Si slot stride (272 B, 16B-aligned)
constexpr int PXB     = 32;   // pixels per block

// DPP quad_perm helpers (VALU pipe): xor1=[1,0,3,2]=0xB1, xor2=[2,3,0,1]=0x4E,
// broadcast lane L = L*0x55.
__device__ __forceinline__ float dpp_xor1(float v) {
    int i = __builtin_bit_cast(int, v);
    i = __builtin_amdgcn_mov_dpp(i, 0xB1, 0xF, 0xF, false);
    return __builtin_bit_cast(float, i);
}
__device__ __forceinline__ float dpp_xor2(float v) {
    int i = __builtin_bit_cast(int, v);
    i = __builtin_amdgcn_mov_dpp(i, 0x4E, 0xF, 0xF, false);
    return __builtin_bit_cast(float, i);
}
__device__ __forceinline__ float dpp_xor(float v, int M) {
    return (M == 1) ? dpp_xor1(v) : dpp_xor2(v);
}
template <int L>
__device__ __forceinline__ float dpp_bcast(float v) {
    int i = __builtin_bit_cast(int, v);
    i = __builtin_amdgcn_mov_dpp(i, L * 0x55, 0xF, 0xF, false);
    return __builtin_bit_cast(float, i);
}

// One Eklundh stage (mask M in {1,2}) on a matrix held as 4 lanes x 2 row-arrays.
// Exchanges 2x2 blocks (s,b) <-> (s^M, b^M) where (s^b)&M != 0. D may alias S.
#define TSTEP(S0, S1, D0, D1, M)                                         \
    _Pragma("unroll")                                                    \
    for (int j_ = 0; j_ < 8; ++j_) {                                     \
        if ((j_ & (2*(M))) == 0) {                                       \
            const int j2_ = j_ | (2*(M));                                \
            const bool a_ = ((s ^ (j_ >> 1)) & (M)) != 0;                \
            float g0_ = a_ ? S0[j_] : S0[j2_];                           \
            float g1_ = a_ ? S1[j_] : S1[j2_];                           \
            float r0_ = dpp_xor(g0_, (M));                               \
            float r1_ = dpp_xor(g1_, (M));                               \
            D0[j_]  = a_ ? r0_ : S0[j_];   D0[j2_] = a_ ? S0[j2_] : r0_; \
            D1[j_]  = a_ ? r1_ : S1[j_];   D1[j2_] = a_ ? S1[j2_] : r1_; \
        }                                                                \
    }

__global__ __launch_bounds__(128, 2) void pm19_kernel(
    const float* __restrict__ mu,
    const float* __restrict__ sigma,
    const float* __restrict__ sigma_inv,
    float* __restrict__ out)
{
    __shared__ float mS[PXB * SSTRIDE];   // Si only: 8704 B/block

    const int tid = threadIdx.x;
    const int s   = tid & 3;     // row-pair id
    const int p   = tid >> 2;    // pixel within block (0..31)

    // XCD-aware chunked swizzle: 8192 blocks = 8 XCDs x 1024
    const int bid = blockIdx.x;
    const int swz = (bid & 7) * 1024 + (bid >> 3);
    const int idx = swz * PXB + p;

    const int x = idx >> 9, y = idx & 511;
    const int ixp = (((x + 1) & 511) << 9) | y;
    const int ixm = (((x - 1) & 511) << 9) | y;
    const int iyp = (x << 9) | ((y + 1) & 511);
    const int iym = (x << 9) | ((y - 1) & 511);

    float* slotS = mS + p * SSTRIDE;

    // ---------------- Si rows 2s,2s+1: load, stage to LDS, KEEP in regs ----------------
    float si0[8], si1[8];
    {
        const float4* q = reinterpret_cast<const float4*>(sigma_inv + (size_t)idx * 64 + s * 16);
        float4 q0 = q[0], q1 = q[1], q2 = q[2], q3 = q[3];
        si0[0]=q0.x; si0[1]=q0.y; si0[2]=q0.z; si0[3]=q0.w;
        si0[4]=q1.x; si0[5]=q1.y; si0[6]=q1.z; si0[7]=q1.w;
        si1[0]=q2.x; si1[1]=q2.y; si1[2]=q2.z; si1[3]=q2.w;
        si1[4]=q3.x; si1[5]=q3.y; si1[6]=q3.z; si1[7]=q3.w;
        float4* w = reinterpret_cast<float4*>(slotS + s * 16);
        w[0] = q0; w[1] = q1; w[2] = q2; w[3] = q3;
    }

    // ---------------- raw dmu quarter (1 f4 per thread), DPP all-gather ----------------
    // lane s=0: dmu0[0:4], s=1: dmu0[4:8], s=2: dmu1[0:4], s=3: dmu1[4:8]
    float dq[4];
    {
        const int plus  = (s < 2) ? ixp : iyp;
        const int minus = (s < 2) ? ixm : iym;
        const int h     = (s & 1) * 4;
        float4 a = *reinterpret_cast<const float4*>(mu + (size_t)plus  * 8 + h);
        float4 b = *reinterpret_cast<const float4*>(mu + (size_t)minus * 8 + h);
        dq[0] = a.x - b.x; dq[1] = a.y - b.y; dq[2] = a.z - b.z; dq[3] = a.w - b.w;
    }

    // ---------------- raw dS rows 2s,2s+1 (registers) ----------------
    float dsx0[8], dsx1[8], dsy0[8], dsy1[8];
    {
        const float4* a = reinterpret_cast<const float4*>(sigma + (size_t)ixp * 64 + s * 16);
        const float4* b = reinterpret_cast<const float4*>(sigma + (size_t)ixm * 64 + s * 16);
        float4 a0=a[0],a1=a[1],a2=a[2],a3=a[3], b0=b[0],b1=b[1],b2=b[2],b3=b[3];
        dsx0[0]=a0.x-b0.x; dsx0[1]=a0.y-b0.y; dsx0[2]=a0.z-b0.z; dsx0[3]=a0.w-b0.w;
        dsx0[4]=a1.x-b1.x; dsx0[5]=a1.y-b1.y; dsx0[6]=a1.z-b1.z; dsx0[7]=a1.w-b1.w;
        dsx1[0]=a2.x-b2.x; dsx1[1]=a2.y-b2.y; dsx1[2]=a2.z-b2.z; dsx1[3]=a2.w-b2.w;
        dsx1[4]=a3.x-b3.x; dsx1[5]=a3.y-b3.y; dsx1[6]=a3.z-b3.z; dsx1[7]=a3.w-b3.w;
    }
    {
        const float4* a = reinterpret_cast<const float4*>(sigma + (size_t)iyp * 64 + s * 16);
        const float4* b = reinterpret_cast<const float4*>(sigma + (size_t)iym * 64 + s * 16);
        float4 a0=a[0],a1=a[1],a2=a[2],a3=a[3], b0=b[0],b1=b[1],b2=b[2],b3=b[3];
        dsy0[0]=a0.x-b0.x; dsy0[1]=a0.y-b0.y; dsy0[2]=a0.z-b0.z; dsy0[3]=a0.w-b0.w;
        dsy0[4]=a1.x-b1.x; dsy0[5]=a1.y-b1.y; dsy0[6]=a1.z-b1.z; dsy0[7]=a1.w-b1.w;
        dsy1[0]=a2.x-b2.x; dsy1[1]=a2.y-b2.y; dsy1[2]=a2.z-b2.z; dsy1[3]=a2.w-b2.w;
        dsy1[4]=a3.x-b3.x; dsy1[5]=a3.y-b3.y; dsy1[6]=a3.z-b3.z; dsy1[7]=a3.w-b3.w;
    }

    // ---------------- assemble full dmu via DPP quad broadcasts ----------------
    float dm0[8], dm1[8];
    #pragma unroll
    for (int j = 0; j < 4; ++j) {
        dm0[j]     = dpp_bcast<0>(dq[j]);
        dm0[4 + j] = dpp_bcast<1>(dq[j]);
        dm1[j]     = dpp_bcast<2>(dq[j]);
        dm1[4 + j] = dpp_bcast<3>(dq[j]);
    }

    // ---------------- mean term partials (rows 2s,2s+1; si + dm die here) ----------------
    float mp0, mp1, mp2;
    {
        float d0a = dm0[0], d0b = dm0[1], d1a = dm1[0], d1b = dm1[1];
        #pragma unroll
        for (int c = 1; c < 4; ++c) {
            if (s == c) {
                d0a = dm0[2*c]; d0b = dm0[2*c+1];
                d1a = dm1[2*c]; d1b = dm1[2*c+1];
            }
        }
        float v00 = 0.f, v01 = 0.f, v10 = 0.f, v11 = 0.f;
        #pragma unroll
        for (int j = 0; j < 8; ++j) {
            v00 = fmaf(si0[j], dm0[j], v00);   // (Si dmu0)[2s]
            v01 = fmaf(si0[j], dm1[j], v01);   // (Si dmu1)[2s]
            v10 = fmaf(si1[j], dm0[j], v10);   // (Si dmu0)[2s+1]
            v11 = fmaf(si1[j], dm1[j], v11);   // (Si dmu1)[2s+1]
        }
        mp0 = d0a * v00 + d0b * v10;
        mp1 = d0a * v01 + d0b * v11;
        mp2 = d1a * v01 + d1b * v11;
    }

    __syncthreads();   // Si staged (the only barrier)

    // ---------------- fused stream: X and Y rows from ONE pass over Si ----------------
    float X0[8], X1[8], Y0[8], Y1[8];
    #pragma unroll
    for (int k = 0; k < 8; ++k) {
        float row[8];
        *reinterpret_cast<float4*>(&row[0]) = *reinterpret_cast<const float4*>(slotS + k * 8);
        *reinterpret_cast<float4*>(&row[4]) = *reinterpret_cast<const float4*>(slotS + k * 8 + 4);
        float x0 = 0.f, x1 = 0.f, y0 = 0.f, y1 = 0.f;
        #pragma unroll
        for (int j = 0; j < 8; ++j) {
            x0 = fmaf(dsx0[j], row[j], x0);
            x1 = fmaf(dsx1[j], row[j], x1);
            y0 = fmaf(dsy0[j], row[j], y0);
            y1 = fmaf(dsy1[j], row[j], y1);
        }
        X0[k] = x0; X1[k] = x1; Y0[k] = y0; Y1[k] = y1;
    }
    // dsx, dsy dead

    // ---------------- Eklundh DPP transposes ----------------
    float TX0[8], TX1[8], TY0[8], TY1[8];
    TSTEP(X0, X1, TX0, TX1, 1)
    TSTEP(TX0, TX1, TX0, TX1, 2)     // TX = X^T blocks
    TSTEP(Y0, Y1, TY0, TY1, 1)
    TSTEP(TY0, TY1, TY0, TY1, 2)     // TY = Y^T blocks

    // ---------------- cov partials (rows 2s,2s+1) ----------------
    float c00 = 0.f, c01 = 0.f, c11 = 0.f;
    #pragma unroll
    for (int k = 0; k < 8; ++k) {
        const float xt0 = (k & 1) ? TX1[k ^ 1] : TX0[k];       // X[k][2s]
        const float xt1 = (k & 1) ? TX1[k]     : TX0[k ^ 1];   // X[k][2s+1]
        const float yt0 = (k & 1) ? TY1[k ^ 1] : TY0[k];       // Y[k][2s]
        const float yt1 = (k & 1) ? TY1[k]     : TY0[k ^ 1];   // Y[k][2s+1]
        c00 = fmaf(X0[k], xt0, c00); c00 = fmaf(X1[k], xt1, c00);
        c01 = fmaf(Y0[k], xt0, c01); c01 = fmaf(Y1[k], xt1, c01);
        c11 = fmaf(Y0[k], yt0, c11); c11 = fmaf(Y1[k], yt1, c11);
    }

    // ---------------- combine per-thread (mp AND c are quad-partial), reduce g ----------------
    float g0 = 0.25f * mp0 + 0.125f * c00;   // G[0][0] partial
    float g1 = 0.25f * mp1 + 0.125f * c01;   // G[0][1] partial
    float g3 = 0.25f * mp2 + 0.125f * c11;   // G[1][1] partial
    g0 += dpp_xor1(g0); g0 += dpp_xor2(g0);
    g1 += dpp_xor1(g1); g1 += dpp_xor2(g1);
    g3 += dpp_xor1(g3); g3 += dpp_xor2(g3);

    float val = (s == 0) ? g0 : ((s == 3) ? g3 : g1);
    out[(size_t)idx * 4 + s] = val;
}

extern "C" void kernel_launch(void* const* d_in, const int* in_sizes, int n_in,
                              void* d_out, int out_size, void* d_ws, size_t ws_size,
                              hipStream_t stream) {
    const float* mu        = (const float*)d_in[0];
    const float* sigma     = (const float*)d_in[1];
    const float* sigma_inv = (const float*)d_in[2];
    float* out = (float*)d_out;

    // 262144 pixels / 32 per block = 8192 blocks (divisible by 8 -> bijective swizzle)
    pm19_kernel<<<8192, 128, 0, stream>>>(mu, sigma, sigma_inv, out);
}

// Round 20
// 31.827 us; speedup vs baseline: 1.0471x; 1.0471x over previous
//
#include <hip/hip_runtime.h>

// PullbackMetric, 4 threads/pixel (thread s owns rows {2s,2s+1}), ZERO LDS.
// G[m][n] = dmu_m^T Si dmu_n + 0.5 tr( (Si dSig_m)(Si dSig_n) )
// Si = Si^T. X = dSx*Si, Y = dSy*Si rows via ONE fused stream over Si rows.
// KEY: the full Si lives distributed across the quad (lane t holds rows 2t,2t+1
// from its own load), so the stream sources rows via DPP quad-broadcast
// (quad_perm[t,t,t,t], compile-time owner) instead of LDS: 20 DS ops -> 0,
// no __syncthreads, no LDS allocation, bank conflicts structurally zero.
// dmu via DPP quad all-gather. Cov traces via 2-stage Eklundh DPP transpose.
// Epilogue: mp AND c are quad-partial -> combine g per-thread, then reduce g.
// launch_bounds(128,2): VGPR cap 256/2=128 (rule confirmed R1..R15); peak live
// ~100 floats fits -> no spill (WRITE_SIZE tripwire).

constexpr int PXB = 32;   // pixels per block (128 threads)

// DPP quad_perm helpers (VALU pipe): xor1=[1,0,3,2]=0xB1, xor2=[2,3,0,1]=0x4E,
// broadcast lane L = L*0x55.
__device__ __forceinline__ float dpp_xor1(float v) {
    int i = __builtin_bit_cast(int, v);
    i = __builtin_amdgcn_mov_dpp(i, 0xB1, 0xF, 0xF, false);
    return __builtin_bit_cast(float, i);
}
__device__ __forceinline__ float dpp_xor2(float v) {
    int i = __builtin_bit_cast(int, v);
    i = __builtin_amdgcn_mov_dpp(i, 0x4E, 0xF, 0xF, false);
    return __builtin_bit_cast(float, i);
}
__device__ __forceinline__ float dpp_xor(float v, int M) {
    return (M == 1) ? dpp_xor1(v) : dpp_xor2(v);
}
template <int L>
__device__ __forceinline__ float dpp_bcast(float v) {
    int i = __builtin_bit_cast(int, v);
    i = __builtin_amdgcn_mov_dpp(i, L * 0x55, 0xF, 0xF, false);
    return __builtin_bit_cast(float, i);
}

// One Eklundh stage (mask M in {1,2}) on a matrix held as 4 lanes x 2 row-arrays.
// Exchanges 2x2 blocks (s,b) <-> (s^M, b^M) where (s^b)&M != 0. D may alias S.
#define TSTEP(S0, S1, D0, D1, M)                                         \
    _Pragma("unroll")                                                    \
    for (int j_ = 0; j_ < 8; ++j_) {                                     \
        if ((j_ & (2*(M))) == 0) {                                       \
            const int j2_ = j_ | (2*(M));                                \
            const bool a_ = ((s ^ (j_ >> 1)) & (M)) != 0;                \
            float g0_ = a_ ? S0[j_] : S0[j2_];                           \
            float g1_ = a_ ? S1[j_] : S1[j2_];                           \
            float r0_ = dpp_xor(g0_, (M));                               \
            float r1_ = dpp_xor(g1_, (M));                               \
            D0[j_]  = a_ ? r0_ : S0[j_];   D0[j2_] = a_ ? S0[j2_] : r0_; \
            D1[j_]  = a_ ? r1_ : S1[j_];   D1[j2_] = a_ ? S1[j2_] : r1_; \
        }                                                                \
    }

// Stream one Si row (row K, owner lane K/2, source array si0/si1) broadcast to
// the quad; accumulate X[K] = dot(dsx_row, Si_K) and Y[K] = dot(dsy_row, Si_K).
#define DO_ROW(K, OWNER, SRC)                                            \
    {                                                                    \
        float row_[8];                                                   \
        _Pragma("unroll")                                                \
        for (int j_ = 0; j_ < 8; ++j_) row_[j_] = dpp_bcast<OWNER>(SRC[j_]); \
        float x0_ = 0.f, x1_ = 0.f, y0_ = 0.f, y1_ = 0.f;                \
        _Pragma("unroll")                                                \
        for (int j_ = 0; j_ < 8; ++j_) {                                 \
            x0_ = fmaf(dsx0[j_], row_[j_], x0_);                         \
            x1_ = fmaf(dsx1[j_], row_[j_], x1_);                         \
            y0_ = fmaf(dsy0[j_], row_[j_], y0_);                         \
            y1_ = fmaf(dsy1[j_], row_[j_], y1_);                         \
        }                                                                \
        X0[K] = x0_; X1[K] = x1_; Y0[K] = y0_; Y1[K] = y1_;              \
    }

__global__ __launch_bounds__(128, 2) void pm20_kernel(
    const float* __restrict__ mu,
    const float* __restrict__ sigma,
    const float* __restrict__ sigma_inv,
    float* __restrict__ out)
{
    const int tid = threadIdx.x;
    const int s   = tid & 3;     // row-pair id (owns rows 2s, 2s+1)
    const int p   = tid >> 2;    // pixel within block (0..31)

    // XCD-aware chunked swizzle: 8192 blocks = 8 XCDs x 1024
    const int bid = blockIdx.x;
    const int swz = (bid & 7) * 1024 + (bid >> 3);
    const int idx = swz * PXB + p;

    const int x = idx >> 9, y = idx & 511;
    const int ixp = (((x + 1) & 511) << 9) | y;
    const int ixm = (((x - 1) & 511) << 9) | y;
    const int iyp = (x << 9) | ((y + 1) & 511);
    const int iym = (x << 9) | ((y - 1) & 511);

    // ---------------- Si rows 2s,2s+1 (registers; quad holds full Si) ----------------
    float si0[8], si1[8];
    {
        const float4* q = reinterpret_cast<const float4*>(sigma_inv + (size_t)idx * 64 + s * 16);
        float4 q0 = q[0], q1 = q[1], q2 = q[2], q3 = q[3];
        si0[0]=q0.x; si0[1]=q0.y; si0[2]=q0.z; si0[3]=q0.w;
        si0[4]=q1.x; si0[5]=q1.y; si0[6]=q1.z; si0[7]=q1.w;
        si1[0]=q2.x; si1[1]=q2.y; si1[2]=q2.z; si1[3]=q2.w;
        si1[4]=q3.x; si1[5]=q3.y; si1[6]=q3.z; si1[7]=q3.w;
    }

    // ---------------- raw dmu quarter (1 f4 per thread), DPP all-gather ----------------
    // lane s=0: dmu0[0:4], s=1: dmu0[4:8], s=2: dmu1[0:4], s=3: dmu1[4:8]
    float dq[4];
    {
        const int plus  = (s < 2) ? ixp : iyp;
        const int minus = (s < 2) ? ixm : iym;
        const int h     = (s & 1) * 4;
        float4 a = *reinterpret_cast<const float4*>(mu + (size_t)plus  * 8 + h);
        float4 b = *reinterpret_cast<const float4*>(mu + (size_t)minus * 8 + h);
        dq[0] = a.x - b.x; dq[1] = a.y - b.y; dq[2] = a.z - b.z; dq[3] = a.w - b.w;
    }

    // ---------------- raw dS rows 2s,2s+1 (registers) ----------------
    float dsx0[8], dsx1[8], dsy0[8], dsy1[8];
    {
        const float4* a = reinterpret_cast<const float4*>(sigma + (size_t)ixp * 64 + s * 16);
        const float4* b = reinterpret_cast<const float4*>(sigma + (size_t)ixm * 64 + s * 16);
        float4 a0=a[0],a1=a[1],a2=a[2],a3=a[3], b0=b[0],b1=b[1],b2=b[2],b3=b[3];
        dsx0[0]=a0.x-b0.x; dsx0[1]=a0.y-b0.y; dsx0[2]=a0.z-b0.z; dsx0[3]=a0.w-b0.w;
        dsx0[4]=a1.x-b1.x; dsx0[5]=a1.y-b1.y; dsx0[6]=a1.z-b1.z; dsx0[7]=a1.w-b1.w;
        dsx1[0]=a2.x-b2.x; dsx1[1]=a2.y-b2.y; dsx1[2]=a2.z-b2.z; dsx1[3]=a2.w-b2.w;
        dsx1[4]=a3.x-b3.x; dsx1[5]=a3.y-b3.y; dsx1[6]=a3.z-b3.z; dsx1[7]=a3.w-b3.w;
    }
    {
        const float4* a = reinterpret_cast<const float4*>(sigma + (size_t)iyp * 64 + s * 16);
        const float4* b = reinterpret_cast<const float4*>(sigma + (size_t)iym * 64 + s * 16);
        float4 a0=a[0],a1=a[1],a2=a[2],a3=a[3], b0=b[0],b1=b[1],b2=b[2],b3=b[3];
        dsy0[0]=a0.x-b0.x; dsy0[1]=a0.y-b0.y; dsy0[2]=a0.z-b0.z; dsy0[3]=a0.w-b0.w;
        dsy0[4]=a1.x-b1.x; dsy0[5]=a1.y-b1.y; dsy0[6]=a1.z-b1.z; dsy0[7]=a1.w-b1.w;
        dsy1[0]=a2.x-b2.x; dsy1[1]=a2.y-b2.y; dsy1[2]=a2.z-b2.z; dsy1[3]=a2.w-b2.w;
        dsy1[4]=a3.x-b3.x; dsy1[5]=a3.y-b3.y; dsy1[6]=a3.z-b3.z; dsy1[7]=a3.w-b3.w;
    }

    // ---------------- assemble full dmu via DPP quad broadcasts ----------------
    float dm0[8], dm1[8];
    #pragma unroll
    for (int j = 0; j < 4; ++j) {
        dm0[j]     = dpp_bcast<0>(dq[j]);
        dm0[4 + j] = dpp_bcast<1>(dq[j]);
        dm1[j]     = dpp_bcast<2>(dq[j]);
        dm1[4 + j] = dpp_bcast<3>(dq[j]);
    }

    // ---------------- mean term partials (rows 2s,2s+1; dm dies here) ----------------
    float mp0, mp1, mp2;
    {
        float d0a = dm0[0], d0b = dm0[1], d1a = dm1[0], d1b = dm1[1];
        #pragma unroll
        for (int c = 1; c < 4; ++c) {
            if (s == c) {
                d0a = dm0[2*c]; d0b = dm0[2*c+1];
                d1a = dm1[2*c]; d1b = dm1[2*c+1];
            }
        }
        float v00 = 0.f, v01 = 0.f, v10 = 0.f, v11 = 0.f;
        #pragma unroll
        for (int j = 0; j < 8; ++j) {
            v00 = fmaf(si0[j], dm0[j], v00);   // (Si dmu0)[2s]
            v01 = fmaf(si0[j], dm1[j], v01);   // (Si dmu1)[2s]
            v10 = fmaf(si1[j], dm0[j], v10);   // (Si dmu0)[2s+1]
            v11 = fmaf(si1[j], dm1[j], v11);   // (Si dmu1)[2s+1]
        }
        mp0 = d0a * v00 + d0b * v10;
        mp1 = d0a * v01 + d0b * v11;
        mp2 = d1a * v01 + d1b * v11;
    }

    // ---------------- fused stream: Si rows via DPP broadcast, X and Y together ----------------
    // Row k of Si lives in lane k/2 (si0 if k even, si1 if k odd). No LDS, no barrier.
    float X0[8], X1[8], Y0[8], Y1[8];
    DO_ROW(0, 0, si0)  DO_ROW(1, 0, si1)
    DO_ROW(2, 1, si0)  DO_ROW(3, 1, si1)
    DO_ROW(4, 2, si0)  DO_ROW(5, 2, si1)
    DO_ROW(6, 3, si0)  DO_ROW(7, 3, si1)
    // si, dsx, dsy dead

    // ---------------- Eklundh DPP transposes ----------------
    float TX0[8], TX1[8], TY0[8], TY1[8];
    TSTEP(X0, X1, TX0, TX1, 1)
    TSTEP(TX0, TX1, TX0, TX1, 2)     // TX = X^T blocks
    TSTEP(Y0, Y1, TY0, TY1, 1)
    TSTEP(TY0, TY1, TY0, TY1, 2)     // TY = Y^T blocks

    // ---------------- cov partials (rows 2s,2s+1) ----------------
    float c00 = 0.f, c01 = 0.f, c11 = 0.f;
    #pragma unroll
    for (int k = 0; k < 8; ++k) {
        const float xt0 = (k & 1) ? TX1[k ^ 1] : TX0[k];       // X[k][2s]
        const float xt1 = (k & 1) ? TX1[k]     : TX0[k ^ 1];   // X[k][2s+1]
        const float yt0 = (k & 1) ? TY1[k ^ 1] : TY0[k];       // Y[k][2s]
        const float yt1 = (k & 1) ? TY1[k]     : TY0[k ^ 1];   // Y[k][2s+1]
        c00 = fmaf(X0[k], xt0, c00); c00 = fmaf(X1[k], xt1, c00);
        c01 = fmaf(Y0[k], xt0, c01); c01 = fmaf(Y1[k], xt1, c01);
        c11 = fmaf(Y0[k], yt0, c11); c11 = fmaf(Y1[k], yt1, c11);
    }

    // ---------------- combine per-thread (mp AND c quad-partial), reduce g ----------------
    float g0 = 0.25f * mp0 + 0.125f * c00;   // G[0][0] partial
    float g1 = 0.25f * mp1 + 0.125f * c01;   // G[0][1] partial
    float g3 = 0.25f * mp2 + 0.125f * c11;   // G[1][1] partial
    g0 += dpp_xor1(g0); g0 += dpp_xor2(g0);
    g1 += dpp_xor1(g1); g1 += dpp_xor2(g1);
    g3 += dpp_xor1(g3); g3 += dpp_xor2(g3);

    float val = (s == 0) ? g0 : ((s == 3) ? g3 : g1);
    out[(size_t)idx * 4 + s] = val;
}

extern "C" void kernel_launch(void* const* d_in, const int* in_sizes, int n_in,
                              void* d_out, int out_size, void* d_ws, size_t ws_size,
                              hipStream_t stream) {
    const float* mu        = (const float*)d_in[0];
    const float* sigma     = (const float*)d_in[1];
    const float* sigma_inv = (const float*)d_in[2];
    float* out = (float*)d_out;

    // 262144 pixels / 32 per block = 8192 blocks (divisible by 8 -> bijective swizzle)
    pm20_kernel<<<8192, 128, 0, stream>>>(mu, sigma, sigma_inv, out);
}

// Round 21
// 30.528 us; speedup vs baseline: 1.0917x; 1.0425x over previous
//
#include <hip/hip_runtime.h>

// PullbackMetric, 4 threads/pixel (thread s owns rows {2s,2s+1}).
// G[m][n] = dmu_m^T Si dmu_n + 0.5 tr( (Si dSig_m)(Si dSig_n) )
// Si = Si^T, dSig symmetric. X = dSx*Si, Y = dSy*Si rows from register dS rows
// dotted with Si rows streamed (quad-broadcast) from LDS; Si staged once/pixel.
// Quad shuffles on the VALU pipe via DPP quad_perm (not DS). Sequential X->Y
// phases keep the live set at 76 VGPR -> the winning ~6-waves/SIMD class.
// FINAL: best measured variant (R17, 30.66us). The frontier across 5 designs
// (DS 0..45 ops, VGPR 64..120, occupancy class 2..8 waves) is flat at 30-33us;
// kernel is exposed-latency-bound with no pipe >50% at bench pace.

constexpr int SSTRIDE = 68;   // Si slot stride (272 B, 16B-aligned)
constexpr int DSTRIDE = 20;   // dmu slot stride (80 B)
constexpr int PXB     = 32;   // pixels per block

// DPP quad_perm lane-xor (VALU pipe, not DS): xor1 = [1,0,3,2] = 0xB1,
// xor2 = [2,3,0,1] = 0x4E. All lanes active -> masks 0xF/0xF, bound_ctrl false.
__device__ __forceinline__ float dpp_xor1(float v) {
    int i = __builtin_bit_cast(int, v);
    i = __builtin_amdgcn_mov_dpp(i, 0xB1, 0xF, 0xF, false);
    return __builtin_bit_cast(float, i);
}
__device__ __forceinline__ float dpp_xor2(float v) {
    int i = __builtin_bit_cast(int, v);
    i = __builtin_amdgcn_mov_dpp(i, 0x4E, 0xF, 0xF, false);
    return __builtin_bit_cast(float, i);
}
__device__ __forceinline__ float dpp_xor(float v, int M) {
    return (M == 1) ? dpp_xor1(v) : dpp_xor2(v);
}

// One Eklundh stage (mask M in {1,2}) on a matrix held as 4 lanes x 2 row-arrays.
// Exchanges 2x2 blocks (s,b) <-> (s^M, b^M) where (s^b)&M != 0. D may alias S.
#define TSTEP(S0, S1, D0, D1, M)                                         \
    _Pragma("unroll")                                                    \
    for (int j_ = 0; j_ < 8; ++j_) {                                     \
        if ((j_ & (2*(M))) == 0) {                                       \
            const int j2_ = j_ | (2*(M));                                \
            const bool a_ = ((s ^ (j_ >> 1)) & (M)) != 0;                \
            float g0_ = a_ ? S0[j_] : S0[j2_];                           \
            float g1_ = a_ ? S1[j_] : S1[j2_];                           \
            float r0_ = dpp_xor(g0_, (M));                               \
            float r1_ = dpp_xor(g1_, (M));                               \
            D0[j_]  = a_ ? r0_ : S0[j_];   D0[j2_] = a_ ? S0[j2_] : r0_; \
            D1[j_]  = a_ ? r1_ : S1[j_];   D1[j2_] = a_ ? S1[j2_] : r1_; \
        }                                                                \
    }

__global__ __launch_bounds__(128, 3) void pm21_kernel(
    const float* __restrict__ mu,
    const float* __restrict__ sigma,
    const float* __restrict__ sigma_inv,
    float* __restrict__ out)
{
    __shared__ float mS[PXB * SSTRIDE];   // Si: 8704 B
    __shared__ float mD[PXB * DSTRIDE];   // dmu: 2560 B  (11264 B total)

    const int tid = threadIdx.x;
    const int s   = tid & 3;     // row-pair id
    const int p   = tid >> 2;    // pixel within block (0..31)

    // XCD-aware chunked swizzle: 8192 blocks = 8 XCDs x 1024
    const int bid = blockIdx.x;
    const int swz = (bid & 7) * 1024 + (bid >> 3);
    const int idx = swz * PXB + p;

    const int x = idx >> 9, y = idx & 511;
    const int ixp = (((x + 1) & 511) << 9) | y;
    const int ixm = (((x - 1) & 511) << 9) | y;
    const int iyp = (x << 9) | ((y + 1) & 511);
    const int iym = (x << 9) | ((y - 1) & 511);

    float* slotS = mS + p * SSTRIDE;
    float* slotD = mD + p * DSTRIDE;

    // ---------------- Si rows 2s,2s+1 -> LDS (transient regs) ----------------
    {
        const float4* q = reinterpret_cast<const float4*>(sigma_inv + (size_t)idx * 64 + s * 16);
        float4 q0 = q[0], q1 = q[1], q2 = q[2], q3 = q[3];
        float4* w = reinterpret_cast<float4*>(slotS + s * 16);
        w[0] = q0; w[1] = q1; w[2] = q2; w[3] = q3;
    }

    // ---------------- cooperative raw dmu quarter (1 f4 per thread) ----------------
    // slotD layout: [dmu0 raw (8) | dmu1 raw (8)]
    {
        const int plus  = (s < 2) ? ixp : iyp;
        const int minus = (s < 2) ? ixm : iym;
        const int h     = (s & 1) * 4;
        float4 a = *reinterpret_cast<const float4*>(mu + (size_t)plus  * 8 + h);
        float4 b = *reinterpret_cast<const float4*>(mu + (size_t)minus * 8 + h);
        float4 d;
        d.x = a.x - b.x; d.y = a.y - b.y; d.z = a.z - b.z; d.w = a.w - b.w;
        *reinterpret_cast<float4*>(slotD + s * 4) = d;
    }

    // ---------------- raw dS rows 2s,2s+1 (registers, no staging) ----------------
    float dsx0[8], dsx1[8], dsy0[8], dsy1[8];
    {
        const float4* a = reinterpret_cast<const float4*>(sigma + (size_t)ixp * 64 + s * 16);
        const float4* b = reinterpret_cast<const float4*>(sigma + (size_t)ixm * 64 + s * 16);
        float4 a0=a[0],a1=a[1],a2=a[2],a3=a[3], b0=b[0],b1=b[1],b2=b[2],b3=b[3];
        dsx0[0]=a0.x-b0.x; dsx0[1]=a0.y-b0.y; dsx0[2]=a0.z-b0.z; dsx0[3]=a0.w-b0.w;
        dsx0[4]=a1.x-b1.x; dsx0[5]=a1.y-b1.y; dsx0[6]=a1.z-b1.z; dsx0[7]=a1.w-b1.w;
        dsx1[0]=a2.x-b2.x; dsx1[1]=a2.y-b2.y; dsx1[2]=a2.z-b2.z; dsx1[3]=a2.w-b2.w;
        dsx1[4]=a3.x-b3.x; dsx1[5]=a3.y-b3.y; dsx1[6]=a3.z-b3.z; dsx1[7]=a3.w-b3.w;
    }
    {
        const float4* a = reinterpret_cast<const float4*>(sigma + (size_t)iyp * 64 + s * 16);
        const float4* b = reinterpret_cast<const float4*>(sigma + (size_t)iym * 64 + s * 16);
        float4 a0=a[0],a1=a[1],a2=a[2],a3=a[3], b0=b[0],b1=b[1],b2=b[2],b3=b[3];
        dsy0[0]=a0.x-b0.x; dsy0[1]=a0.y-b0.y; dsy0[2]=a0.z-b0.z; dsy0[3]=a0.w-b0.w;
        dsy0[4]=a1.x-b1.x; dsy0[5]=a1.y-b1.y; dsy0[6]=a1.z-b1.z; dsy0[7]=a1.w-b1.w;
        dsy1[0]=a2.x-b2.x; dsy1[1]=a2.y-b2.y; dsy1[2]=a2.z-b2.z; dsy1[3]=a2.w-b2.w;
        dsy1[4]=a3.x-b3.x; dsy1[5]=a3.y-b3.y; dsy1[6]=a3.z-b3.z; dsy1[7]=a3.w-b3.w;
    }

    __syncthreads();   // Si + dmu staged (the only barrier, 2 waves)

    // ---------------- mean term ----------------
    float mp0, mp1, mp2;
    {
        float dm0[8], dm1[8];
        *reinterpret_cast<float4*>(&dm0[0]) = *reinterpret_cast<const float4*>(slotD + 0);
        *reinterpret_cast<float4*>(&dm0[4]) = *reinterpret_cast<const float4*>(slotD + 4);
        *reinterpret_cast<float4*>(&dm1[0]) = *reinterpret_cast<const float4*>(slotD + 8);
        *reinterpret_cast<float4*>(&dm1[4]) = *reinterpret_cast<const float4*>(slotD + 12);
        // own components via compile-time unrolled select (no scratch)
        float d0a = dm0[0], d0b = dm0[1], d1a = dm1[0], d1b = dm1[1];
        #pragma unroll
        for (int c = 1; c < 4; ++c) {
            if (s == c) {
                d0a = dm0[2*c]; d0b = dm0[2*c+1];
                d1a = dm1[2*c]; d1b = dm1[2*c+1];
            }
        }
        float v00 = 0.f, v01 = 0.f, v10 = 0.f, v11 = 0.f;
        {
            float rowa[8];   // Si row 2s
            *reinterpret_cast<float4*>(&rowa[0]) = *reinterpret_cast<const float4*>(slotS + (2*s) * 8);
            *reinterpret_cast<float4*>(&rowa[4]) = *reinterpret_cast<const float4*>(slotS + (2*s) * 8 + 4);
            #pragma unroll
            for (int j = 0; j < 8; ++j) {
                v00 = fmaf(rowa[j], dm0[j], v00);
                v01 = fmaf(rowa[j], dm1[j], v01);
            }
        }
        {
            float rowb[8];   // Si row 2s+1
            *reinterpret_cast<float4*>(&rowb[0]) = *reinterpret_cast<const float4*>(slotS + (2*s+1) * 8);
            *reinterpret_cast<float4*>(&rowb[4]) = *reinterpret_cast<const float4*>(slotS + (2*s+1) * 8 + 4);
            #pragma unroll
            for (int j = 0; j < 8; ++j) {
                v10 = fmaf(rowb[j], dm0[j], v10);
                v11 = fmaf(rowb[j], dm1[j], v11);
            }
        }
        mp0 = d0a * v00 + d0b * v10;
        mp1 = d0a * v01 + d0b * v11;
        mp2 = d1a * v01 + d1b * v11;
    }

    // ---------------- phase X: stream Si, X rows, transpose, c00 ----------------
    float c00 = 0.f, c01 = 0.f, c11 = 0.f;
    float TX0[8], TX1[8];
    {
        float X0[8], X1[8];
        #pragma unroll
        for (int k = 0; k < 8; ++k) {
            float row[8];
            *reinterpret_cast<float4*>(&row[0]) = *reinterpret_cast<const float4*>(slotS + k * 8);
            *reinterpret_cast<float4*>(&row[4]) = *reinterpret_cast<const float4*>(slotS + k * 8 + 4);
            float x0 = 0.f, x1 = 0.f;
            #pragma unroll
            for (int j = 0; j < 8; ++j) {
                x0 = fmaf(dsx0[j], row[j], x0);
                x1 = fmaf(dsx1[j], row[j], x1);
            }
            X0[k] = x0; X1[k] = x1;   // X[2s][k], X[2s+1][k]
        }
        TSTEP(X0, X1, TX0, TX1, 1)       // stage 1 (copies into TX)
        TSTEP(TX0, TX1, TX0, TX1, 2)     // stage 2 in-place
        #pragma unroll
        for (int k = 0; k < 8; ++k) {
            const float xt0 = (k & 1) ? TX1[k ^ 1] : TX0[k];       // X[k][2s]
            const float xt1 = (k & 1) ? TX1[k]     : TX0[k ^ 1];   // X[k][2s+1]
            c00 = fmaf(X0[k], xt0, c00);
            c00 = fmaf(X1[k], xt1, c00);
        }
    }   // X0/X1, dsx dead; TX kept for c01

    // ---------------- phase Y: stream Si, Y rows, c01, transpose, c11 ----------------
    {
        float Y0[8], Y1[8];
        #pragma unroll
        for (int k = 0; k < 8; ++k) {
            float row[8];
            *reinterpret_cast<float4*>(&row[0]) = *reinterpret_cast<const float4*>(slotS + k * 8);
            *reinterpret_cast<float4*>(&row[4]) = *reinterpret_cast<const float4*>(slotS + k * 8 + 4);
            float y0 = 0.f, y1 = 0.f;
            #pragma unroll
            for (int j = 0; j < 8; ++j) {
                y0 = fmaf(dsy0[j], row[j], y0);
                y1 = fmaf(dsy1[j], row[j], y1);
            }
            Y0[k] = y0; Y1[k] = y1;
        }
        // c01 = sum_k Y[2s,k] X[k,2s] + Y[2s+1,k] X[k,2s+1]  (trace of X*Y)
        #pragma unroll
        for (int k = 0; k < 8; ++k) {
            const float xt0 = (k & 1) ? TX1[k ^ 1] : TX0[k];
            const float xt1 = (k & 1) ? TX1[k]     : TX0[k ^ 1];
            c01 = fmaf(Y0[k], xt0, c01);
            c01 = fmaf(Y1[k], xt1, c01);
        }   // TX dead
        float TY0[8], TY1[8];
        TSTEP(Y0, Y1, TY0, TY1, 1)
        TSTEP(TY0, TY1, TY0, TY1, 2)
        #pragma unroll
        for (int k = 0; k < 8; ++k) {
            const float yt0 = (k & 1) ? TY1[k ^ 1] : TY0[k];       // Y[k][2s]
            const float yt1 = (k & 1) ? TY1[k]     : TY0[k ^ 1];   // Y[k][2s+1]
            c11 = fmaf(Y0[k], yt0, c11);
            c11 = fmaf(Y1[k], yt1, c11);
        }
    }

    // ---------------- combine (fold FD 0.5s), quad-reduce via DPP, write ----------------
    float g0 = 0.25f * mp0 + 0.125f * c00;   // G[0][0]
    float g1 = 0.25f * mp1 + 0.125f * c01;   // G[0][1] == G[1][0]
    float g3 = 0.25f * mp2 + 0.125f * c11;   // G[1][1]
    g0 += dpp_xor1(g0); g0 += dpp_xor2(g0);
    g1 += dpp_xor1(g1); g1 += dpp_xor2(g1);
    g3 += dpp_xor1(g3); g3 += dpp_xor2(g3);

    float val = (s == 0) ? g0 : ((s == 3) ? g3 : g1);
    out[(size_t)idx * 4 + s] = val;
}

extern "C" void kernel_launch(void* const* d_in, const int* in_sizes, int n_in,
                              void* d_out, int out_size, void* d_ws, size_t ws_size,
                              hipStream_t stream) {
    const float* mu        = (const float*)d_in[0];
    const float* sigma     = (const float*)d_in[1];
    const float* sigma_inv = (const float*)d_in[2];
    float* out = (float*)d_out;

    // 262144 pixels / 32 per block = 8192 blocks (divisible by 8 -> bijective swizzle)
    pm21_kernel<<<8192, 128, 0, stream>>>(mu, sigma, sigma_inv, out);
}